// Round 4
// baseline (255.822 us; speedup 1.0000x reference)
//
#include <hip/hip_runtime.h>

// LocallyConnected2d: out[b,o,y,x] = sum_{c,i,j} x[b,c,y+i,x+j] * w[o,c,y,x,i*3+j]
// B=16, C_IN=16, H=W=64, C_OUT=16, KH=KW=3, OH=OW=62.
//
// Round 4: latency attack.
//  - x prefetched one c ahead into registers (fully unrolled c-loop).
//  - c-range split across 2 blocks (atomicAdd, exactly 2 addends -> deterministic;
//    out zero-initialized by a prior kernel on the same stream).
//  - b split across 2 blocks (8 b per block). Grid 62x4x4 = 992 blocks -> ~4
//    blocks/CU, 16 waves/CU = 4 waves/SIMD for stall covering.
//  - w staged via coalesced float2 -> LDS (mod-3 swizzle, ~2-way = free),
//    double-buffered, one barrier per c-iter.

#define CIN   16
#define COUT  16
#define HH    64
#define WW    64
#define OHH   62
#define OWW   62
#define HW    (HH * WW)

#define WOSTR (CIN * OHH * OWW * 9)   // 553536 floats: o stride in w
#define WCSTR (OHH * OWW * 9)         // 34596 floats: c stride in w
#define OROW  388                     // per-o LDS stride in dwords (32*12 + 4 pad)
#define NC    8                       // c's per block

__device__ __forceinline__ int ldsIdx(int o, int xi, int k) {
    int j = k >> 2;                // chunk 0:k0-3, 1:k4-7, 2:k8
    int p = (j + xi) % 3;          // rotate chunks by x -> breaks stride-12 bank pattern
    return o * OROW + xi * 12 + p * 4 + (k & 3);
}

__global__ __launch_bounds__(256, 1)
void zero_out(float* __restrict__ outg) {
    // 984064 floats = 246016 float4; grid 961 x 256 covers exactly
    ((float4*)outg)[blockIdx.x * 256 + threadIdx.x] = make_float4(0.f, 0.f, 0.f, 0.f);
}

__global__ __launch_bounds__(256, 4)
void lc2d(const float* __restrict__ xg,
          const float* __restrict__ wg,
          float* __restrict__ outg)
{
    __shared__ float Wl[2][8 * OROW];   // 2 x 12.4 KB

    const int tid = threadIdx.x;
    const int y   = blockIdx.x;          // 0..61
    const int xh  = blockIdx.y & 1;      // x half
    const int bh  = blockIdx.y >> 1;     // b half
    const int oh  = blockIdx.z & 1;      // o half
    const int ch  = blockIdx.z >> 1;     // c half
    const int x0  = xh * 32;
    const int nx  = xh ? (OWW - 32) : 32;     // 30 or 32 valid positions
    const int M   = nx * 9 / 2;               // float2 per (o,c) run (144 or 135)
    const int tot = 8 * M;
    const int cstart = ch * NC;

    // compute-role indices: tid = xl + og*32 + bg*64
    const int xl  = tid & 31;
    const int og  = (tid >> 5) & 1;      // 4-of-8 o
    const int bg  = tid >> 6;            // 0..3 -> 2 b's each
    const int pos = x0 + xl;
    const bool valid = pos < OWW;
    const int xp  = valid ? pos : (OWW - 1);

    // staging descriptors (c-invariant): flat float2 id -> (o, float-offset in run)
    int st_o[5], st_fo[5];
    bool st_en[5];
    #pragma unroll
    for (int r = 0; r < 5; ++r) {
        int id = tid + 256 * r;
        st_en[r] = id < tot;
        int idc = st_en[r] ? id : 0;
        int o = idc / M;
        st_o[r]  = o;
        st_fo[r] = 2 * (idc - o * M);
    }
    int wr0[5], wr1[5];
    #pragma unroll
    for (int r = 0; r < 5; ++r) {
        int fo = st_fo[r];
        int xi = fo / 9;
        int k  = fo - xi * 9;
        wr0[r] = ldsIdx(st_o[r], xi, k);
        int xi2 = (k == 8) ? xi + 1 : xi;
        int k2  = (k == 8) ? 0 : k + 1;
        wr1[r] = ldsIdx(st_o[r], xi2, k2);
    }

    const float* wbase = wg + (size_t)oh * 8 * WOSTR + (size_t)cstart * WCSTR
                            + (size_t)(y * OWW + x0) * 9;

    // x bases for this thread's 2 b's (at c = cstart)
    const float* xb0 = xg + ((size_t)(bh * 8 + bg * 2 + 0) * CIN + cstart) * HW
                          + (size_t)y * WW + xp;
    const float* xb1 = xg + ((size_t)(bh * 8 + bg * 2 + 1) * CIN + cstart) * HW
                          + (size_t)y * WW + xp;

    // ---- prologue: stage first c into buffer 0; first x tile into regs ----
    float xva[2][2][9];
    {
        float2 pf[5];
        #pragma unroll
        for (int r = 0; r < 5; ++r)
            if (st_en[r])
                pf[r] = *(const float2*)(wbase + (size_t)st_o[r] * WOSTR + st_fo[r]);
        #pragma unroll
        for (int i = 0; i < 3; ++i)
            #pragma unroll
            for (int j = 0; j < 3; ++j) {
                xva[0][0][i * 3 + j] = xb0[i * WW + j];
                xva[0][1][i * 3 + j] = xb1[i * WW + j];
            }
        #pragma unroll
        for (int r = 0; r < 5; ++r) {
            if (st_en[r]) {
                Wl[0][wr0[r]] = pf[r].x;
                Wl[0][wr1[r]] = pf[r].y;
            }
        }
    }
    __syncthreads();

    float acc[4][2];
    #pragma unroll
    for (int t = 0; t < 4; ++t) { acc[t][0] = 0.f; acc[t][1] = 0.f; }

    // per-thread chunk rotation offsets
    const int p0 = (xl % 3) * 4;
    const int p1 = ((xl + 1) % 3) * 4;
    const int p2 = ((xl + 2) % 3) * 4;

    #pragma unroll
    for (int cc = 0; cc < NC; ++cc) {
        const int cu = cc & 1;
        const int nu = cu ^ 1;

        // ---- prefetch next c's x (registers) and w (for LDS) EARLY ----
        float2 npf[5];
        if (cc + 1 < NC) {
            const float* xr0 = xb0 + (size_t)(cc + 1) * HW;
            const float* xr1 = xb1 + (size_t)(cc + 1) * HW;
            #pragma unroll
            for (int i = 0; i < 3; ++i)
                #pragma unroll
                for (int j = 0; j < 3; ++j) {
                    xva[nu][0][i * 3 + j] = xr0[i * WW + j];
                    xva[nu][1][i * 3 + j] = xr1[i * WW + j];
                }
            #pragma unroll
            for (int r = 0; r < 5; ++r)
                if (st_en[r])
                    npf[r] = *(const float2*)(wbase + (size_t)st_o[r] * WOSTR
                                              + (size_t)(cc + 1) * WCSTR + st_fo[r]);
        }

        // ---- compute: 4 o x 2 b x 9 k ----
        const float* cur = Wl[cu];
        #pragma unroll
        for (int t = 0; t < 4; ++t) {
            const int base = (og * 4 + t) * OROW + xl * 12;
            const float4 w0 = *(const float4*)&cur[base + p0];    // k0..3
            const float4 w1 = *(const float4*)&cur[base + p1];    // k4..7
            const float  w8 = cur[base + p2];                     // k8
            #pragma unroll
            for (int b = 0; b < 2; ++b) {
                float s = acc[t][b];
                s = fmaf(w0.x, xva[cu][b][0], s);
                s = fmaf(w0.y, xva[cu][b][1], s);
                s = fmaf(w0.z, xva[cu][b][2], s);
                s = fmaf(w0.w, xva[cu][b][3], s);
                s = fmaf(w1.x, xva[cu][b][4], s);
                s = fmaf(w1.y, xva[cu][b][5], s);
                s = fmaf(w1.z, xva[cu][b][6], s);
                s = fmaf(w1.w, xva[cu][b][7], s);
                s = fmaf(w8,   xva[cu][b][8], s);
                acc[t][b] = s;
            }
        }

        if (cc + 1 < NC) {
            // write prefetched w to the other buffer (read at cc-1, already drained)
            #pragma unroll
            for (int r = 0; r < 5; ++r) {
                if (st_en[r]) {
                    Wl[nu][wr0[r]] = npf[r].x;
                    Wl[nu][wr1[r]] = npf[r].y;
                }
            }
            __syncthreads();
        }
    }

    if (valid) {
        #pragma unroll
        for (int t = 0; t < 4; ++t) {
            const int o = oh * 8 + og * 4 + t;
            #pragma unroll
            for (int b = 0; b < 2; ++b) {
                const int bb = bh * 8 + bg * 2 + b;
                atomicAdd(&outg[((size_t)(bb * COUT + o) * OHH + y) * OWW + pos],
                          acc[t][b]);
            }
        }
    }
}

extern "C" void kernel_launch(void* const* d_in, const int* in_sizes, int n_in,
                              void* d_out, int out_size, void* d_ws, size_t ws_size,
                              hipStream_t stream) {
    const float* x = (const float*)d_in[0];
    const float* w = (const float*)d_in[1];
    float* out = (float*)d_out;

    // out = 16*16*62*62 = 984064 floats = 246016 float4 = 961 blocks x 256
    zero_out<<<dim3(961), dim3(256), 0, stream>>>(out);
    dim3 grid(OHH, 4, 4);   // y, (bh,xh), (ch,oh)
    lc2d<<<grid, dim3(256), 0, stream>>>(x, w, out);
}

// Round 5
// 227.905 us; speedup vs baseline: 1.1225x; 1.1225x over previous
//
#include <hip/hip_runtime.h>

// LocallyConnected2d: out[b,o,y,x] = sum_{c,i,j} x[b,c,y+i,x+j] * w[o,c,y,x,i*3+j]
// B=16, C_IN=16, H=W=64, C_OUT=16, KH=KW=3, OH=OW=62.
//
// Round 5: round-3 body (proven spill-free) + c-split x2 for occupancy.
//  - grid 62 x 2(xh) x 4(ch,oh) = 496 blocks of 512 thr -> 2 blocks/CU,
//    16 waves/CU = 4 waves/SIMD: cross-wave latency hiding (round 3 had 2).
//  - out = sum of 2 c-half partials via atomicAdd (zero-init kernel first,
//    exactly 2 addends per element -> bounded rounding, deterministic enough).
//  - w staged via coalesced float2 -> LDS, mod-3 chunk-rotation swizzle
//    (~2-way conflicts = free), double-buffered, ONE barrier per c-iter.
//  - __launch_bounds__(512,4): VGPR cap 128; body needs ~100. No big
//    per-thread prefetch arrays (that's what spilled round 4).

#define CIN   16
#define COUT  16
#define HH    64
#define WW    64
#define OHH   62
#define OWW   62
#define HW    (HH * WW)

#define WOSTR (CIN * OHH * OWW * 9)   // 553536 floats: o stride in w
#define WCSTR (OHH * OWW * 9)         // 34596 floats: c stride in w
#define OROW  388                     // per-o LDS stride in dwords (32*12 + 4 pad)
#define NC    8                       // c's per block (c-split x2)

__device__ __forceinline__ int ldsIdx(int o, int xi, int k) {
    int j = k >> 2;                // chunk 0:k0-3, 1:k4-7, 2:k8
    int p = (j + xi) % 3;          // rotate chunks by x -> breaks stride-12 bank pattern
    return o * OROW + xi * 12 + p * 4 + (k & 3);
}

__global__ __launch_bounds__(256)
void zero_out(float* __restrict__ outg) {
    // 984064 floats = 246016 float4; grid 961 x 256 covers exactly
    ((float4*)outg)[blockIdx.x * 256 + threadIdx.x] = make_float4(0.f, 0.f, 0.f, 0.f);
}

__global__ __launch_bounds__(512, 4)
void lc2d(const float* __restrict__ xg,
          const float* __restrict__ wg,
          float* __restrict__ outg)
{
    __shared__ float Wl[2][8 * OROW];   // 2 x 12.4 KB

    const int tid = threadIdx.x;
    const int y   = blockIdx.x;          // 0..61
    const int xh  = blockIdx.y;          // 0..1  (x half)
    const int oh  = blockIdx.z & 1;      // o half
    const int ch  = blockIdx.z >> 1;     // c half
    const int x0  = xh * 32;
    const int nx  = xh ? (OWW - 32) : 32;     // 30 or 32 valid positions
    const int M   = nx * 9 / 2;               // float2 per (o,c) run (144 or 135)
    const int tot = 8 * M;
    const int cstart = ch * NC;

    // compute-role indices: tid = xl + og*32 + bg*64
    const int xl  = tid & 31;
    const int og  = (tid >> 5) & 1;      // 4-of-8 o
    const int bg  = tid >> 6;            // 0..7 -> 2 b's each
    const int pos = x0 + xl;
    const bool valid = pos < OWW;
    const int xp  = valid ? pos : (OWW - 1);

    // staging descriptors (c-invariant): flat float2 id -> (o, float-offset in run)
    int st_o[3], st_fo[3];
    bool st_en[3];
    #pragma unroll
    for (int r = 0; r < 3; ++r) {
        int id = tid + 512 * r;
        st_en[r] = id < tot;
        int idc = st_en[r] ? id : 0;
        int o = idc / M;                 // M is block-uniform
        st_o[r]  = o;
        st_fo[r] = 2 * (idc - o * M);
    }
    // precomputed LDS write slots (c-invariant)
    int wr0[3], wr1[3];
    #pragma unroll
    for (int r = 0; r < 3; ++r) {
        int fo = st_fo[r];
        int xi = fo / 9;
        int k  = fo - xi * 9;
        wr0[r] = ldsIdx(st_o[r], xi, k);
        int xi2 = (k == 8) ? xi + 1 : xi;
        int k2  = (k == 8) ? 0 : k + 1;
        wr1[r] = ldsIdx(st_o[r], xi2, k2);
    }

    const float* wbase = wg + (size_t)oh * 8 * WOSTR + (size_t)cstart * WCSTR
                            + (size_t)(y * OWW + x0) * 9;

    // ---- prologue: stage c = cstart into buffer 0 ----
    {
        float2 pf[3];
        #pragma unroll
        for (int r = 0; r < 3; ++r)
            if (st_en[r])
                pf[r] = *(const float2*)(wbase + (size_t)st_o[r] * WOSTR + st_fo[r]);
        #pragma unroll
        for (int r = 0; r < 3; ++r) {
            if (st_en[r]) {
                Wl[0][wr0[r]] = pf[r].x;
                Wl[0][wr1[r]] = pf[r].y;
            }
        }
    }
    __syncthreads();

    float acc[4][2];
    #pragma unroll
    for (int t = 0; t < 4; ++t) { acc[t][0] = 0.f; acc[t][1] = 0.f; }

    // x bases for this thread's 2 b's (at c = cstart)
    const float* xb0 = xg + ((size_t)(bg * 2 + 0) * CIN + cstart) * HW
                          + (size_t)y * WW + xp;
    const float* xb1 = xg + ((size_t)(bg * 2 + 1) * CIN + cstart) * HW
                          + (size_t)y * WW + xp;

    // per-thread chunk rotation offsets (xl fixed)
    const int p0 = (xl % 3) * 4;
    const int p1 = ((xl + 1) % 3) * 4;
    const int p2 = ((xl + 2) % 3) * 4;

    for (int cc = 0; cc < NC; ++cc) {
        const float* cur = Wl[cc & 1];
        float*       nxt = Wl[(cc + 1) & 1];

        // prefetch next c's w into registers (in flight across the compute phase)
        float2 npf[3];
        if (cc + 1 < NC) {
            #pragma unroll
            for (int r = 0; r < 3; ++r)
                if (st_en[r])
                    npf[r] = *(const float2*)(wbase + (size_t)st_o[r] * WOSTR
                                              + (size_t)(cc + 1) * WCSTR + st_fo[r]);
        }

        // x patches for this thread's 2 b's (coalesced 32-lane segments)
        float xv[2][9];
        {
            const float* xr0 = xb0 + (size_t)cc * HW;
            const float* xr1 = xb1 + (size_t)cc * HW;
            #pragma unroll
            for (int i = 0; i < 3; ++i)
                #pragma unroll
                for (int j = 0; j < 3; ++j) {
                    xv[0][i * 3 + j] = xr0[i * WW + j];
                    xv[1][i * 3 + j] = xr1[i * WW + j];
                }
        }

        // 4 o's x 2 b's x 9 k FMAs; W via 2x b128 + 1x b32 LDS reads per o
        #pragma unroll
        for (int t = 0; t < 4; ++t) {
            const int base = (og * 4 + t) * OROW + xl * 12;
            const float4 w0 = *(const float4*)&cur[base + p0];    // k0..3
            const float4 w1 = *(const float4*)&cur[base + p1];    // k4..7
            const float  w8 = cur[base + p2];                     // k8
            #pragma unroll
            for (int b = 0; b < 2; ++b) {
                float s = acc[t][b];
                s = fmaf(w0.x, xv[b][0], s);
                s = fmaf(w0.y, xv[b][1], s);
                s = fmaf(w0.z, xv[b][2], s);
                s = fmaf(w0.w, xv[b][3], s);
                s = fmaf(w1.x, xv[b][4], s);
                s = fmaf(w1.y, xv[b][5], s);
                s = fmaf(w1.z, xv[b][6], s);
                s = fmaf(w1.w, xv[b][7], s);
                s = fmaf(w8,   xv[b][8], s);
                acc[t][b] = s;
            }
        }

        if (cc + 1 < NC) {
            // write prefetched tile to other buffer (its readers drained at
            // the barrier that ended iter cc-1)
            #pragma unroll
            for (int r = 0; r < 3; ++r) {
                if (st_en[r]) {
                    nxt[wr0[r]] = npf[r].x;
                    nxt[wr1[r]] = npf[r].y;
                }
            }
            __syncthreads();   // one barrier per c-iter
        }
    }

    if (valid) {
        #pragma unroll
        for (int t = 0; t < 4; ++t) {
            const int o = oh * 8 + og * 4 + t;
            #pragma unroll
            for (int b = 0; b < 2; ++b) {
                const int bb = bg * 2 + b;
                atomicAdd(&outg[((size_t)(bb * COUT + o) * OHH + y) * OWW + pos],
                          acc[t][b]);
            }
        }
    }
}

extern "C" void kernel_launch(void* const* d_in, const int* in_sizes, int n_in,
                              void* d_out, int out_size, void* d_ws, size_t ws_size,
                              hipStream_t stream) {
    const float* x = (const float*)d_in[0];
    const float* w = (const float*)d_in[1];
    float* out = (float*)d_out;

    // out = 16*16*62*62 = 984064 floats = 246016 float4 = 961 blocks x 256
    zero_out<<<dim3(961), dim3(256), 0, stream>>>(out);
    dim3 grid(OHH, 2, 4);   // y, xh, (ch,oh)
    lc2d<<<grid, dim3(512), 0, stream>>>(x, w, out);
}

// Round 6
// 151.152 us; speedup vs baseline: 1.6925x; 1.5078x over previous
//
#include <hip/hip_runtime.h>

// LocallyConnected2d: out[b,o,y,x] = sum_{c,i,j} x[b,c,y+i,x+j] * w[o,c,y,x,i*3+j]
// B=16, C_IN=16, H=W=64, C_OUT=16, KH=KW=3, OH=OW=62.
//
// Round 6: round-5 dataflow, de-fanged:
//  - __launch_bounds__(512) with NO min-waves arg. (512,4)/(256,4) both forced
//    VGPR=64 -> massive scratch spill (FETCH 176MB/WRITE 293MB, 163us). Round-3's
//    uncapped build was spill-free. Natural ~100 VGPR <= 128 -> 2 blocks/CU.
//  - x loads issued BEFORE w-prefetch: FMAs then wait vmcnt(6) instead of
//    vmcnt(0), so the 6 prefetch loads stay in flight across compute.
//  - c-split x2 (8 c per block) -> 496 blocks -> 16 waves/CU = 4 waves/SIMD.
//    out = 2 atomic addends per element, zero-init kernel first.
//  - w staged via coalesced float2 -> LDS, mod-3 chunk-rotation swizzle,
//    double-buffered, one barrier per c-iter.

#define CIN   16
#define COUT  16
#define HH    64
#define WW    64
#define OHH   62
#define OWW   62
#define HW    (HH * WW)

#define WOSTR (CIN * OHH * OWW * 9)   // 553536 floats: o stride in w
#define WCSTR (OHH * OWW * 9)         // 34596 floats: c stride in w
#define OROW  388                     // per-o LDS stride in dwords (32*12 + 4 pad)
#define NC    8                       // c's per block (c-split x2)

__device__ __forceinline__ int ldsIdx(int o, int xi, int k) {
    int j = k >> 2;                // chunk 0:k0-3, 1:k4-7, 2:k8
    int p = (j + xi) % 3;          // rotate chunks by x -> breaks stride-12 bank pattern
    return o * OROW + xi * 12 + p * 4 + (k & 3);
}

__global__ __launch_bounds__(256)
void zero_out(float* __restrict__ outg) {
    // 984064 floats = 246016 float4; grid 961 x 256 covers exactly
    ((float4*)outg)[blockIdx.x * 256 + threadIdx.x] = make_float4(0.f, 0.f, 0.f, 0.f);
}

__global__ __launch_bounds__(512)
void lc2d(const float* __restrict__ xg,
          const float* __restrict__ wg,
          float* __restrict__ outg)
{
    __shared__ float Wl[2][8 * OROW];   // 2 x 12.4 KB

    const int tid = threadIdx.x;
    const int y   = blockIdx.x;          // 0..61
    const int xh  = blockIdx.y;          // 0..1  (x half)
    const int oh  = blockIdx.z & 1;      // o half
    const int ch  = blockIdx.z >> 1;     // c half
    const int x0  = xh * 32;
    const int nx  = xh ? (OWW - 32) : 32;     // 30 or 32 valid positions
    const int M   = nx * 9 / 2;               // float2 per (o,c) run (144 or 135)
    const int tot = 8 * M;
    const int cstart = ch * NC;

    // compute-role indices: tid = xl + og*32 + bg*64
    const int xl  = tid & 31;
    const int og  = (tid >> 5) & 1;      // 4-of-8 o
    const int bg  = tid >> 6;            // 0..7 -> 2 b's each
    const int pos = x0 + xl;
    const bool valid = pos < OWW;
    const int xp  = valid ? pos : (OWW - 1);

    // staging descriptors (c-invariant): flat float2 id -> (o, float-offset in run)
    int st_o[3], st_fo[3];
    bool st_en[3];
    #pragma unroll
    for (int r = 0; r < 3; ++r) {
        int id = tid + 512 * r;
        st_en[r] = id < tot;
        int idc = st_en[r] ? id : 0;
        int o = idc / M;                 // M is block-uniform
        st_o[r]  = o;
        st_fo[r] = 2 * (idc - o * M);
    }
    // precomputed LDS write slots (c-invariant)
    int wr0[3], wr1[3];
    #pragma unroll
    for (int r = 0; r < 3; ++r) {
        int fo = st_fo[r];
        int xi = fo / 9;
        int k  = fo - xi * 9;
        wr0[r] = ldsIdx(st_o[r], xi, k);
        int xi2 = (k == 8) ? xi + 1 : xi;
        int k2  = (k == 8) ? 0 : k + 1;
        wr1[r] = ldsIdx(st_o[r], xi2, k2);
    }

    const float* wbase = wg + (size_t)oh * 8 * WOSTR + (size_t)cstart * WCSTR
                            + (size_t)(y * OWW + x0) * 9;

    // ---- prologue: stage c = cstart into buffer 0 ----
    {
        float2 pf[3];
        #pragma unroll
        for (int r = 0; r < 3; ++r)
            if (st_en[r])
                pf[r] = *(const float2*)(wbase + (size_t)st_o[r] * WOSTR + st_fo[r]);
        #pragma unroll
        for (int r = 0; r < 3; ++r) {
            if (st_en[r]) {
                Wl[0][wr0[r]] = pf[r].x;
                Wl[0][wr1[r]] = pf[r].y;
            }
        }
    }
    __syncthreads();

    float acc[4][2];
    #pragma unroll
    for (int t = 0; t < 4; ++t) { acc[t][0] = 0.f; acc[t][1] = 0.f; }

    // x bases for this thread's 2 b's (at c = cstart)
    const float* xb0 = xg + ((size_t)(bg * 2 + 0) * CIN + cstart) * HW
                          + (size_t)y * WW + xp;
    const float* xb1 = xg + ((size_t)(bg * 2 + 1) * CIN + cstart) * HW
                          + (size_t)y * WW + xp;

    // per-thread chunk rotation offsets (xl fixed)
    const int p0 = (xl % 3) * 4;
    const int p1 = ((xl + 1) % 3) * 4;
    const int p2 = ((xl + 2) % 3) * 4;

    for (int cc = 0; cc < NC; ++cc) {
        const float* cur = Wl[cc & 1];
        float*       nxt = Wl[(cc + 1) & 1];

        // ---- x patches FIRST (consumed this iter; wait = vmcnt(6)) ----
        float xv[2][9];
        {
            const float* xr0 = xb0 + (size_t)cc * HW;
            const float* xr1 = xb1 + (size_t)cc * HW;
            #pragma unroll
            for (int i = 0; i < 3; ++i)
                #pragma unroll
                for (int j = 0; j < 3; ++j) {
                    xv[0][i * 3 + j] = xr0[i * WW + j];
                    xv[1][i * 3 + j] = xr1[i * WW + j];
                }
        }

        // ---- w prefetch SECOND (consumed after compute; stays in flight) ----
        float2 npf[3];
        if (cc + 1 < NC) {
            #pragma unroll
            for (int r = 0; r < 3; ++r)
                if (st_en[r])
                    npf[r] = *(const float2*)(wbase + (size_t)st_o[r] * WOSTR
                                              + (size_t)(cc + 1) * WCSTR + st_fo[r]);
        }

        // 4 o's x 2 b's x 9 k FMAs; W via 2x b128 + 1x b32 LDS reads per o
        #pragma unroll
        for (int t = 0; t < 4; ++t) {
            const int base = (og * 4 + t) * OROW + xl * 12;
            const float4 w0 = *(const float4*)&cur[base + p0];    // k0..3
            const float4 w1 = *(const float4*)&cur[base + p1];    // k4..7
            const float  w8 = cur[base + p2];                     // k8
            #pragma unroll
            for (int b = 0; b < 2; ++b) {
                float s = acc[t][b];
                s = fmaf(w0.x, xv[b][0], s);
                s = fmaf(w0.y, xv[b][1], s);
                s = fmaf(w0.z, xv[b][2], s);
                s = fmaf(w0.w, xv[b][3], s);
                s = fmaf(w1.x, xv[b][4], s);
                s = fmaf(w1.y, xv[b][5], s);
                s = fmaf(w1.z, xv[b][6], s);
                s = fmaf(w1.w, xv[b][7], s);
                s = fmaf(w8,   xv[b][8], s);
                acc[t][b] = s;
            }
        }

        if (cc + 1 < NC) {
            // write prefetched tile to other buffer (its readers drained at
            // the barrier that ended iter cc-1)
            #pragma unroll
            for (int r = 0; r < 3; ++r) {
                if (st_en[r]) {
                    nxt[wr0[r]] = npf[r].x;
                    nxt[wr1[r]] = npf[r].y;
                }
            }
            __syncthreads();   // one barrier per c-iter
        }
    }

    if (valid) {
        #pragma unroll
        for (int t = 0; t < 4; ++t) {
            const int o = oh * 8 + og * 4 + t;
            #pragma unroll
            for (int b = 0; b < 2; ++b) {
                const int bb = bg * 2 + b;
                atomicAdd(&outg[((size_t)(bb * COUT + o) * OHH + y) * OWW + pos],
                          acc[t][b]);
            }
        }
    }
}

extern "C" void kernel_launch(void* const* d_in, const int* in_sizes, int n_in,
                              void* d_out, int out_size, void* d_ws, size_t ws_size,
                              hipStream_t stream) {
    const float* x = (const float*)d_in[0];
    const float* w = (const float*)d_in[1];
    float* out = (float*)d_out;

    // out = 16*16*62*62 = 984064 floats = 246016 float4 = 961 blocks x 256
    zero_out<<<dim3(961), dim3(256), 0, stream>>>(out);
    dim3 grid(OHH, 2, 4);   // y, xh, (ch,oh)
    lc2d<<<grid, dim3(512), 0, stream>>>(x, w, out);
}

// Round 7
// 94.325 us; speedup vs baseline: 2.7121x; 1.6025x over previous
//
#include <hip/hip_runtime.h>

// LocallyConnected2d: out[b,o,y,x] = sum_{c,i,j} x[b,c,y+i,x+j] * w[o,c,y,x,i*3+j]
// B=16, C_IN=16, H=W=64, C_OUT=16, KH=KW=3, OH=OW=62.
//
// Round 7:
//  - LDS layout [o][k][xi]: reads AND writes lane-stride-1 -> conflict-free
//    (round-6 counters showed 3.3M conflict cycles with the strided layout).
//    Staging loads w in read-layout order (9 b32 gathers, lane-stride 9);
//    TA cost ~2.4us/CU, eliminates all LDS conflicts.
//  - __launch_bounds__(256, 2): VGPR cap 256. (.,4)->64 and bare 512->128 both
//    spilled (FETCH/WRITE ballooned to 100-300MB). Body needs ~110.
//  - Thread tile 4o x 4b: halves LDS re-reads per element vs 2b tile.
//  - c-split x2 (8 c/block) -> grid 62x2x2x2=496 -> 2 blocks/CU, 2 waves/SIMD,
//    independent blocks interleave at barriers. atomicAdd epilogue (2 addends),
//    zero-init kernel first.
//  - Per c-iter: x loads first (compute waits vmcnt(9), not 0), then w
//    prefetch (stays in flight across compute), double-buffered LDS, one barrier.

#define CIN   16
#define COUT  16
#define HH    64
#define WW    64
#define OHH   62
#define OWW   62
#define HW    (HH * WW)

#define WOSTR (CIN * OHH * OWW * 9)   // 553536 floats: o stride in w
#define WCSTR (OHH * OWW * 9)         // 34596 floats: c stride in w
#define NC    8                       // c's per block (c-split x2)
#define OTILE 288                     // per-o LDS stride: 9 k * 32 xi

__global__ __launch_bounds__(256)
void zero_out(float* __restrict__ outg) {
    // 984064 floats = 246016 float4 = 961 * 256
    ((float4*)outg)[blockIdx.x * 256 + threadIdx.x] = make_float4(0.f, 0.f, 0.f, 0.f);
}

__global__ __launch_bounds__(256, 2)
void lc2d(const float* __restrict__ xg,
          const float* __restrict__ wg,
          float* __restrict__ outg)
{
    __shared__ float Wl[2][8 * OTILE];   // 2 x 9216 B

    const int tid = threadIdx.x;
    const int y   = blockIdx.x;          // 0..61
    const int xh  = blockIdx.y;          // 0..1  (x half)
    const int oh  = blockIdx.z & 1;      // o half
    const int ch  = blockIdx.z >> 1;     // c half
    const int x0  = xh * 32;
    const int cstart = ch * NC;

    // compute roles: tid = xl + og*32 + bg*64
    const int xl  = tid & 31;
    const int og  = (tid >> 5) & 1;      // picks 4-of-8 o
    const int bg  = tid >> 6;            // 0..3 -> 4 b's each
    const int pos = x0 + xl;
    const bool valid = pos < OWW;
    const int xp  = valid ? pos : (OWW - 1);

    // staging roles: q = o-within-block (0..7), sxi = xi (0..31)
    const int q   = tid >> 5;
    const int sxi = tid & 31;
    const int sx  = (x0 + sxi < OWW) ? (x0 + sxi) : (OWW - 1);  // in-bounds clamp
    const float* wst = wg + (size_t)(oh * 8 + q) * WOSTR + (size_t)cstart * WCSTR
                          + (size_t)(y * OWW + sx) * 9;
    const int wrbase = q * OTILE + sxi;  // + r*32; lane-stride-1 -> conflict-free

    // ---- prologue: stage c = cstart into buffer 0 ----
    {
        float pf[9];
        #pragma unroll
        for (int r = 0; r < 9; ++r) pf[r] = wst[r];
        #pragma unroll
        for (int r = 0; r < 9; ++r) Wl[0][wrbase + r * 32] = pf[r];
    }
    __syncthreads();

    float acc[4][4];
    #pragma unroll
    for (int t = 0; t < 4; ++t)
        #pragma unroll
        for (int b = 0; b < 4; ++b) acc[t][b] = 0.f;

    // x base for (b= bg*4, c=cstart, y, xp)
    const float* xbb = xg + ((size_t)(bg * 4) * CIN + cstart) * HW
                          + (size_t)y * WW + xp;

    for (int cc = 0; cc < NC; ++cc) {
        const float* cur = Wl[cc & 1];
        float*       nxt = Wl[(cc + 1) & 1];

        // ---- x patches FIRST (consumed this iter) ----
        float xv[4][9];
        #pragma unroll
        for (int b = 0; b < 4; ++b) {
            const float* xr = xbb + ((size_t)b * CIN + cc) * HW;
            #pragma unroll
            for (int i = 0; i < 3; ++i)
                #pragma unroll
                for (int j = 0; j < 3; ++j)
                    xv[b][i * 3 + j] = xr[i * WW + j];
        }

        // ---- w prefetch SECOND (in flight across compute; vmcnt(9) floor) ----
        float pf[9];
        if (cc + 1 < NC) {
            const float* ws = wst + (size_t)(cc + 1) * WCSTR;
            #pragma unroll
            for (int r = 0; r < 9; ++r) pf[r] = ws[r];
        }

        // ---- compute: 4 o x 4 b x 9 k; LDS reads lane-consecutive (read2-able) ----
        #pragma unroll
        for (int t = 0; t < 4; ++t) {
            const float* wb = &cur[(og * 4 + t) * OTILE + xl];
            float wv[9];
            #pragma unroll
            for (int k = 0; k < 9; ++k) wv[k] = wb[k * 32];
            #pragma unroll
            for (int b = 0; b < 4; ++b) {
                float s = acc[t][b];
                #pragma unroll
                for (int k = 0; k < 9; ++k)
                    s = fmaf(wv[k], xv[b][k], s);
                acc[t][b] = s;
            }
        }

        if (cc + 1 < NC) {
            // readers of `nxt` drained at the barrier that ended iter cc-1
            #pragma unroll
            for (int r = 0; r < 9; ++r) nxt[wrbase + r * 32] = pf[r];
            __syncthreads();   // one barrier per c-iter
        }
    }

    if (valid) {
        #pragma unroll
        for (int t = 0; t < 4; ++t) {
            const int o = oh * 8 + og * 4 + t;
            #pragma unroll
            for (int b = 0; b < 4; ++b) {
                const int bb = bg * 4 + b;
                atomicAdd(&outg[((size_t)(bb * COUT + o) * OHH + y) * OWW + pos],
                          acc[t][b]);
            }
        }
    }
}

extern "C" void kernel_launch(void* const* d_in, const int* in_sizes, int n_in,
                              void* d_out, int out_size, void* d_ws, size_t ws_size,
                              hipStream_t stream) {
    const float* x = (const float*)d_in[0];
    const float* w = (const float*)d_in[1];
    float* out = (float*)d_out;

    zero_out<<<dim3(961), dim3(256), 0, stream>>>(out);
    dim3 grid(OHH, 2, 4);   // y, xh, (ch,oh)
    lc2d<<<grid, dim3(256), 0, stream>>>(x, w, out);
}